// Round 1
// baseline (1358.035 us; speedup 1.0000x reference)
//
#include <hip/hip_runtime.h>

// WaveNet (nsynth batch-folding) on MI355X.
// Key identity: batch-folding dilation == dilated conv over one 8192-sample
// stream with j = l*2 + n; fold-d conv taps are at j +- 2d, zero-padded at
// stream boundaries. Whole net = 30 fused {K3-conv(G,F) -> gate -> 1x1 thru/skip}
// layers on H[8192][256], bf16 MFMA with fp32 masters for H and S.

#define TS 8192
#define NL 30

typedef __attribute__((ext_vector_type(8))) short bf16x8;
typedef __attribute__((ext_vector_type(4))) float f32x4;

__device__ __forceinline__ unsigned short f2bf(float f) {
    union { float f; unsigned int u; } v; v.f = f;
    unsigned int u = v.u;
    u += 0x7fffu + ((u >> 16) & 1u);   // RNE
    return (unsigned short)(u >> 16);
}

// ---------------------------------------------------------------------------
// Weight prep: fp32 -> bf16 with layout transforms.
// Wgf[k][t][o][ci], o in [0,512): 0..255 = gate, 256..511 = feat  (tap t split out)
// Wts[k][o][ci],    o in [0,512): 0..255 = thru, 256..511 = skip
// Wib[so][ci] (iskip), Wfb[co][so] (final)
// ---------------------------------------------------------------------------
__global__ void prep_weights_kernel(
    const float* __restrict__ gw, const float* __restrict__ fw,
    const float* __restrict__ tw, const float* __restrict__ sw,
    const float* __restrict__ iw, const float* __restrict__ fnw,
    unsigned short* __restrict__ Wgf, unsigned short* __restrict__ Wts,
    unsigned short* __restrict__ Wib, unsigned short* __restrict__ Wfb)
{
    const int idx = blockIdx.x * blockDim.x + threadIdx.x;
    const int stride = gridDim.x * blockDim.x;
    const int n_gf = NL * 3 * 512 * 256;
    for (int i = idx; i < n_gf; i += stride) {
        int ci = i & 255;
        int o  = (i >> 8) & 511;
        int r  = i >> 17;      // k*3 + t
        int t  = r % 3;
        int k  = r / 3;
        float v = (o < 256) ? gw[((k * 256 + o) * 256 + ci) * 3 + t]
                            : fw[((k * 256 + (o - 256)) * 256 + ci) * 3 + t];
        Wgf[i] = f2bf(v);
    }
    const int n_ts = NL * 512 * 256;
    for (int i = idx; i < n_ts; i += stride) {
        int ci = i & 255;
        int o  = (i >> 8) & 511;
        int k  = i >> 17;
        float v = (o < 256) ? tw[(k * 256 + o) * 256 + ci]
                            : sw[(k * 256 + (o - 256)) * 256 + ci];
        Wts[i] = f2bf(v);
    }
    for (int i = idx; i < 256 * 256; i += stride) Wib[i] = f2bf(iw[i]);
    for (int i = idx; i < 256 * 256; i += stride) Wfb[i] = f2bf(fnw[i]);
}

// ---------------------------------------------------------------------------
// Init conv: H0[j][co] = init_b[co] + sum_t init_w[co][t] * x_stream(j + 2t - 2)
// x_stream(i) = x[(i&1)][0][i>>1]
// ---------------------------------------------------------------------------
__global__ void init_kernel(const float* __restrict__ x,
                            const float* __restrict__ init_w,
                            const float* __restrict__ init_b,
                            float* __restrict__ Hf,
                            unsigned short* __restrict__ Hb)
{
    const int j  = blockIdx.x;     // 0..8191
    const int co = threadIdx.x;    // 0..255
    float acc = init_b[co];
    #pragma unroll
    for (int t = 0; t < 3; ++t) {
        int i = j + 2 * t - 2;
        if (i >= 0 && i < TS)
            acc += init_w[co * 3 + t] * x[(i & 1) * 4096 + (i >> 1)];
    }
    Hf[(j << 8) + co] = acc;
    Hb[(j << 8) + co] = f2bf(acc);
}

// ---------------------------------------------------------------------------
// iskip: S[j][so] = ib[so] + sum_ci Wib[so][ci] * H0[j][ci]
// M=8192 (j) x N=256 (so) x K=256, A/B fragments straight from global.
// ---------------------------------------------------------------------------
__global__ __launch_bounds__(512)
void iskip_kernel(const unsigned short* __restrict__ Hb,
                  const unsigned short* __restrict__ Wib,
                  const float* __restrict__ ib,
                  float* __restrict__ S)
{
    const int tid  = threadIdx.x;
    const int lane = tid & 63;
    const int w    = tid >> 6;
    const int j0   = blockIdx.x * 32;
    const int arow = lane & 15;
    const int krow = lane >> 4;
    const int c0   = w * 32;

    f32x4 acc[2][2];
    #pragma unroll
    for (int rt = 0; rt < 2; ++rt)
        #pragma unroll
        for (int fc = 0; fc < 2; ++fc) {
            const float b = ib[c0 + fc * 16 + arow];
            acc[rt][fc] = (f32x4){b, b, b, b};
        }

    #pragma unroll
    for (int kc = 0; kc < 8; ++kc) {
        const int koff = kc * 32 + krow * 8;
        const bf16x8 a0 = *(const bf16x8*)(Hb + ((j0 + arow) << 8) + koff);
        const bf16x8 a1 = *(const bf16x8*)(Hb + ((j0 + 16 + arow) << 8) + koff);
        const bf16x8 b0 = *(const bf16x8*)(Wib + ((c0 + arow) << 8) + koff);
        const bf16x8 b1 = *(const bf16x8*)(Wib + ((c0 + 16 + arow) << 8) + koff);
        acc[0][0] = __builtin_amdgcn_mfma_f32_16x16x32_bf16(a0, b0, acc[0][0], 0, 0, 0);
        acc[1][0] = __builtin_amdgcn_mfma_f32_16x16x32_bf16(a1, b0, acc[1][0], 0, 0, 0);
        acc[0][1] = __builtin_amdgcn_mfma_f32_16x16x32_bf16(a0, b1, acc[0][1], 0, 0, 0);
        acc[1][1] = __builtin_amdgcn_mfma_f32_16x16x32_bf16(a1, b1, acc[1][1], 0, 0, 0);
    }

    #pragma unroll
    for (int rt = 0; rt < 2; ++rt)
        #pragma unroll
        for (int fc = 0; fc < 2; ++fc)
            #pragma unroll
            for (int i = 0; i < 4; ++i) {
                const int row = rt * 16 + krow * 4 + i;
                S[((j0 + row) << 8) + c0 + fc * 16 + arow] = acc[rt][fc][i];
            }
}

// ---------------------------------------------------------------------------
// Fused layer kernel. Block = 32 stream samples, 512 threads (8 waves).
// Phase 1: GF[32][512] = im2col_d(H) @ Wgf^T  (wave w owns gate cols [32w,32w+32)
//          and feat cols [32w,32w+32) so res is wave-local)
// Phase 2: out2[32][512] = res @ Wts^T; cols 0..255 -> H update, 256..511 -> S.
// A tiles & res go through XOR-swizzled LDS; B (weights) streamed from L2.
// ---------------------------------------------------------------------------
__global__ __launch_bounds__(512)
void layer_kernel(const unsigned short* __restrict__ Hb_in,
                  const float* __restrict__ Hf_in,
                  float* __restrict__ Hf_out,
                  unsigned short* __restrict__ Hb_out,
                  const unsigned short* __restrict__ Wgf_k,  // [3][512][256]
                  const unsigned short* __restrict__ Wts_k,  // [512][256]
                  const float* __restrict__ gb,              // [256]
                  const float* __restrict__ fb,              // [256]
                  float* __restrict__ S,
                  unsigned short* __restrict__ Sb,
                  const int d, const int write_sb)
{
    __shared__ __align__(16) unsigned short A_lds[3 * 32 * 256];   // 48 KB
    __shared__ __align__(16) unsigned short res_lds[32 * 256];     // 16 KB

    const int tid  = threadIdx.x;
    const int lane = tid & 63;
    const int w    = tid >> 6;
    const int j0   = blockIdx.x * 32;
    const int arow = lane & 15;
    const int krow = lane >> 4;

    // ---- stage A: 3 taps x 32 rows x 256ch bf16, row-XOR-swizzled (T2/G4) ----
    for (int c = tid; c < 3 * 32 * 32; c += 512) {
        const int c16 = c & 31;
        const int m   = (c >> 5) & 31;
        const int t   = c >> 10;
        const int r   = j0 + m + (t - 1) * d;
        uint4 v = make_uint4(0u, 0u, 0u, 0u);
        if (r >= 0 && r < TS)
            v = *(const uint4*)(Hb_in + (r << 8) + (c16 << 3));
        const int sb = (c16 << 4) ^ ((m & 7) << 4);
        *(uint4*)(A_lds + ((t * 32 + m) << 8) + (sb >> 1)) = v;
    }
    __syncthreads();

    // ---- phase 1: G, F accumulation ----
    const int cg0  = w * 32;
    const int aswz = (arow & 7) << 4;

    f32x4 accG[2][2], accF[2][2];
    #pragma unroll
    for (int rt = 0; rt < 2; ++rt)
        #pragma unroll
        for (int fc = 0; fc < 2; ++fc) {
            const float g = gb[cg0 + fc * 16 + arow];
            const float f = fb[cg0 + fc * 16 + arow];
            accG[rt][fc] = (f32x4){g, g, g, g};
            accF[rt][fc] = (f32x4){f, f, f, f};
        }

    for (int t = 0; t < 3; ++t) {
        const unsigned short* Wg = Wgf_k + ((t * 512 + cg0) << 8);
        const unsigned short* Wf = Wgf_k + ((t * 512 + 256 + cg0) << 8);
        const unsigned short* At = A_lds + ((t * 32 + arow) << 8);
        #pragma unroll
        for (int kc = 0; kc < 8; ++kc) {
            const int cb   = kc * 64 + krow * 16;
            const int aoff = (cb ^ aswz) >> 1;
            const bf16x8 a0 = *(const bf16x8*)(At + aoff);
            const bf16x8 a1 = *(const bf16x8*)(At + (16 << 8) + aoff);
            const int koff = kc * 32 + krow * 8;
            const bf16x8 bg0 = *(const bf16x8*)(Wg + (arow << 8) + koff);
            const bf16x8 bg1 = *(const bf16x8*)(Wg + ((16 + arow) << 8) + koff);
            const bf16x8 bf0 = *(const bf16x8*)(Wf + (arow << 8) + koff);
            const bf16x8 bf1 = *(const bf16x8*)(Wf + ((16 + arow) << 8) + koff);
            accG[0][0] = __builtin_amdgcn_mfma_f32_16x16x32_bf16(a0, bg0, accG[0][0], 0, 0, 0);
            accG[1][0] = __builtin_amdgcn_mfma_f32_16x16x32_bf16(a1, bg0, accG[1][0], 0, 0, 0);
            accG[0][1] = __builtin_amdgcn_mfma_f32_16x16x32_bf16(a0, bg1, accG[0][1], 0, 0, 0);
            accG[1][1] = __builtin_amdgcn_mfma_f32_16x16x32_bf16(a1, bg1, accG[1][1], 0, 0, 0);
            accF[0][0] = __builtin_amdgcn_mfma_f32_16x16x32_bf16(a0, bf0, accF[0][0], 0, 0, 0);
            accF[1][0] = __builtin_amdgcn_mfma_f32_16x16x32_bf16(a1, bf0, accF[1][0], 0, 0, 0);
            accF[0][1] = __builtin_amdgcn_mfma_f32_16x16x32_bf16(a0, bf1, accF[0][1], 0, 0, 0);
            accF[1][1] = __builtin_amdgcn_mfma_f32_16x16x32_bf16(a1, bf1, accF[1][1], 0, 0, 0);
        }
    }

    // ---- res = sigmoid(G) * tanh(F), wave-local, -> swizzled LDS ----
    #pragma unroll
    for (int rt = 0; rt < 2; ++rt)
        #pragma unroll
        for (int fc = 0; fc < 2; ++fc)
            #pragma unroll
            for (int i = 0; i < 4; ++i) {
                const float g = accG[rt][fc][i];
                const float f = accF[rt][fc][i];
                const float rr = (1.0f / (1.0f + __expf(-g))) * tanhf(f);
                const int row = rt * 16 + krow * 4 + i;
                const int col = cg0 + fc * 16 + arow;
                res_lds[(row << 8) + (((col << 1) ^ ((row & 7) << 4)) >> 1)] = f2bf(rr);
            }
    __syncthreads();

    // ---- phase 2: out2 = res @ Wts^T ----
    f32x4 acc2[2][4];
    #pragma unroll
    for (int rt = 0; rt < 2; ++rt)
        #pragma unroll
        for (int fc = 0; fc < 4; ++fc)
            acc2[rt][fc] = (f32x4){0.f, 0.f, 0.f, 0.f};

    const int c0 = w * 64;
    #pragma unroll
    for (int kc = 0; kc < 8; ++kc) {
        const int cb   = kc * 64 + krow * 16;
        const int aoff = (cb ^ aswz) >> 1;
        const bf16x8 a0 = *(const bf16x8*)(res_lds + (arow << 8) + aoff);
        const bf16x8 a1 = *(const bf16x8*)(res_lds + ((16 + arow) << 8) + aoff);
        const int koff = kc * 32 + krow * 8;
        #pragma unroll
        for (int fc = 0; fc < 4; ++fc) {
            const bf16x8 b = *(const bf16x8*)(Wts_k + ((c0 + fc * 16 + arow) << 8) + koff);
            acc2[0][fc] = __builtin_amdgcn_mfma_f32_16x16x32_bf16(a0, b, acc2[0][fc], 0, 0, 0);
            acc2[1][fc] = __builtin_amdgcn_mfma_f32_16x16x32_bf16(a1, b, acc2[1][fc], 0, 0, 0);
        }
    }

    // ---- epilogue: waves 0..3 -> H residual update; waves 4..7 -> S RMW ----
    if (w < 4) {
        #pragma unroll
        for (int rt = 0; rt < 2; ++rt)
            #pragma unroll
            for (int fc = 0; fc < 4; ++fc)
                #pragma unroll
                for (int i = 0; i < 4; ++i) {
                    const int row = rt * 16 + krow * 4 + i;
                    const int cc  = c0 + fc * 16 + arow;
                    const int g   = ((j0 + row) << 8) + cc;
                    const float v = Hf_in[g] + acc2[rt][fc][i];
                    Hf_out[g] = v;
                    Hb_out[g] = f2bf(v);
                }
    } else {
        const int cs0 = c0 - 256;
        #pragma unroll
        for (int rt = 0; rt < 2; ++rt)
            #pragma unroll
            for (int fc = 0; fc < 4; ++fc)
                #pragma unroll
                for (int i = 0; i < 4; ++i) {
                    const int row = rt * 16 + krow * 4 + i;
                    const int so  = cs0 + fc * 16 + arow;
                    const int g   = ((j0 + row) << 8) + so;
                    const float v = S[g] + acc2[rt][fc][i];
                    S[g] = v;
                    if (write_sb) Sb[g] = f2bf(v);
                }
    }
}

// ---------------------------------------------------------------------------
// Final: out[n][co][l] = final_b[co] + sum_so Wfb[co][so] * S[j=2l+n][so]
// Swapped GEMM orientation: M=co (A=Wfb), N=j (B=Sb) -> stores are 32B granules.
// ---------------------------------------------------------------------------
__global__ __launch_bounds__(512)
void final_kernel(const unsigned short* __restrict__ Sb,
                  const unsigned short* __restrict__ Wfb,
                  const float* __restrict__ fbias,
                  float* __restrict__ out)
{
    const int tid  = threadIdx.x;
    const int lane = tid & 63;
    const int w    = tid >> 6;
    const int j0   = blockIdx.x * 32;   // j tile
    const int arow = lane & 15;
    const int krow = lane >> 4;
    const int m0   = w * 32;            // co rows for this wave

    f32x4 acc[2][2];
    #pragma unroll
    for (int rt = 0; rt < 2; ++rt)
        #pragma unroll
        for (int fc = 0; fc < 2; ++fc)
            acc[rt][fc] = (f32x4){0.f, 0.f, 0.f, 0.f};

    #pragma unroll
    for (int kc = 0; kc < 8; ++kc) {
        const int koff = kc * 32 + krow * 8;
        const bf16x8 a0 = *(const bf16x8*)(Wfb + ((m0 + arow) << 8) + koff);
        const bf16x8 a1 = *(const bf16x8*)(Wfb + ((m0 + 16 + arow) << 8) + koff);
        const bf16x8 b0 = *(const bf16x8*)(Sb + ((j0 + arow) << 8) + koff);
        const bf16x8 b1 = *(const bf16x8*)(Sb + ((j0 + 16 + arow) << 8) + koff);
        acc[0][0] = __builtin_amdgcn_mfma_f32_16x16x32_bf16(a0, b0, acc[0][0], 0, 0, 0);
        acc[1][0] = __builtin_amdgcn_mfma_f32_16x16x32_bf16(a1, b0, acc[1][0], 0, 0, 0);
        acc[0][1] = __builtin_amdgcn_mfma_f32_16x16x32_bf16(a0, b1, acc[0][1], 0, 0, 0);
        acc[1][1] = __builtin_amdgcn_mfma_f32_16x16x32_bf16(a1, b1, acc[1][1], 0, 0, 0);
    }

    #pragma unroll
    for (int rt = 0; rt < 2; ++rt)
        #pragma unroll
        for (int fc = 0; fc < 2; ++fc)
            #pragma unroll
            for (int i = 0; i < 4; ++i) {
                const int co = m0 + rt * 16 + krow * 4 + i;
                const int jj = j0 + fc * 16 + arow;
                out[((jj & 1) << 20) + (co << 12) + (jj >> 1)] = acc[rt][fc][i] + fbias[co];
            }
}

// ---------------------------------------------------------------------------
extern "C" void kernel_launch(void* const* d_in, const int* in_sizes, int n_in,
                              void* d_out, int out_size, void* d_ws, size_t ws_size,
                              hipStream_t stream)
{
    const float* x       = (const float*)d_in[0];
    const float* init_w  = (const float*)d_in[1];
    const float* init_b  = (const float*)d_in[2];
    const float* iskip_w = (const float*)d_in[3];
    const float* iskip_b = (const float*)d_in[4];
    const float* gate_w  = (const float*)d_in[5];
    const float* gate_b  = (const float*)d_in[6];
    const float* feat_w  = (const float*)d_in[7];
    const float* feat_b  = (const float*)d_in[8];
    const float* skip_w  = (const float*)d_in[9];
    const float* thru_w  = (const float*)d_in[10];
    const float* final_w = (const float*)d_in[11];
    const float* final_b = (const float*)d_in[12];

    char* ws = (char*)d_ws;
    size_t off = 0;
    auto alloc = [&](size_t bytes) {
        void* p = ws + off;
        off += (bytes + 255) & ~(size_t)255;
        return p;
    };
    unsigned short* Wgf = (unsigned short*)alloc((size_t)NL * 3 * 512 * 256 * 2);
    unsigned short* Wts = (unsigned short*)alloc((size_t)NL * 512 * 256 * 2);
    unsigned short* Wib = (unsigned short*)alloc(256 * 256 * 2);
    unsigned short* Wfb = (unsigned short*)alloc(256 * 256 * 2);
    float*          Hf0 = (float*)alloc((size_t)TS * 256 * 4);
    float*          Hf1 = (float*)alloc((size_t)TS * 256 * 4);
    unsigned short* Hb0 = (unsigned short*)alloc((size_t)TS * 256 * 2);
    unsigned short* Hb1 = (unsigned short*)alloc((size_t)TS * 256 * 2);
    float*          Sf  = (float*)alloc((size_t)TS * 256 * 4);
    unsigned short* Sbb = (unsigned short*)alloc((size_t)TS * 256 * 2);

    prep_weights_kernel<<<2048, 256, 0, stream>>>(gate_w, feat_w, thru_w, skip_w,
                                                  iskip_w, final_w, Wgf, Wts, Wib, Wfb);
    init_kernel<<<TS, 256, 0, stream>>>(x, init_w, init_b, Hf0, Hb0);
    iskip_kernel<<<256, 512, 0, stream>>>(Hb0, Wib, iskip_b, Sf);

    float* hfi = Hf0;          float* hfo = Hf1;
    unsigned short* hbi = Hb0; unsigned short* hbo = Hb1;
    for (int k = 0; k < NL; ++k) {
        const int d = 2 << (k % 10);   // stream dilation = 2 * 2^(k%10)
        layer_kernel<<<256, 512, 0, stream>>>(
            hbi, hfi, hfo, hbo,
            Wgf + (size_t)k * 3 * 512 * 256,
            Wts + (size_t)k * 512 * 256,
            gate_b + k * 256, feat_b + k * 256,
            Sf, Sbb, d, (k == NL - 1) ? 1 : 0);
        float* tf = hfi; hfi = hfo; hfo = tf;
        unsigned short* tb = hbi; hbi = hbo; hbo = tb;
    }

    final_kernel<<<256, 512, 0, stream>>>(Sbb, Wfb, final_b, (float*)d_out);
}

// Round 2
// 976.970 us; speedup vs baseline: 1.3900x; 1.3900x over previous
//
#include <hip/hip_runtime.h>

// WaveNet (nsynth batch-folding) on MI355X.
// Stream identity: batch-folding dilation == dilated conv over one 8192-sample
// stream with j = l*2 + n; fold-d conv taps at j +- 2d, zero-padded at stream
// boundaries. Net = 30 fused {K3 conv (G,F) -> gate -> 1x1 thru/skip} layers on
// H[8192][256]; bf16 MFMA, fp32 masters for H and S.
//
// v2: weights streamed L2 -> LDS via global_load_lds in a per-wave
// double-buffered pipeline (each wave stages only the 64 B-rows it consumes ->
// no barriers in the main loop, counted vmcnt(4) only).

#define TS 8192
#define NL 30

typedef __attribute__((ext_vector_type(8))) short bf16x8;
typedef __attribute__((ext_vector_type(4))) float f32x4;

__device__ __forceinline__ unsigned short f2bf(float f) {
    union { float f; unsigned int u; } v; v.f = f;
    unsigned int u = v.u;
    u += 0x7fffu + ((u >> 16) & 1u);   // RNE
    return (unsigned short)(u >> 16);
}

__device__ __forceinline__ void gload_lds16(const void* g, void* l) {
    __builtin_amdgcn_global_load_lds(
        (const __attribute__((address_space(1))) void*)g,
        (__attribute__((address_space(3))) void*)l, 16, 0, 0);
}

#define WAITCNT_VM4() asm volatile("s_waitcnt vmcnt(4)" ::: "memory")
#define WAITCNT_VM0() asm volatile("s_waitcnt vmcnt(0)" ::: "memory")

// ---------------------------------------------------------------------------
// Weight prep (unchanged): fp32 -> bf16 with layout transforms.
// Wgf[k][t][o][ci], o in [0,512): 0..255 gate, 256..511 feat (tap t split out)
// Wts[k][o][ci],    o in [0,512): 0..255 thru, 256..511 skip
// ---------------------------------------------------------------------------
__global__ void prep_weights_kernel(
    const float* __restrict__ gw, const float* __restrict__ fw,
    const float* __restrict__ tw, const float* __restrict__ sw,
    const float* __restrict__ iw, const float* __restrict__ fnw,
    unsigned short* __restrict__ Wgf, unsigned short* __restrict__ Wts,
    unsigned short* __restrict__ Wib, unsigned short* __restrict__ Wfb)
{
    const int idx = blockIdx.x * blockDim.x + threadIdx.x;
    const int stride = gridDim.x * blockDim.x;
    const int n_gf = NL * 3 * 512 * 256;
    for (int i = idx; i < n_gf; i += stride) {
        int ci = i & 255;
        int o  = (i >> 8) & 511;
        int r  = i >> 17;      // k*3 + t
        int t  = r % 3;
        int k  = r / 3;
        float v = (o < 256) ? gw[((k * 256 + o) * 256 + ci) * 3 + t]
                            : fw[((k * 256 + (o - 256)) * 256 + ci) * 3 + t];
        Wgf[i] = f2bf(v);
    }
    const int n_ts = NL * 512 * 256;
    for (int i = idx; i < n_ts; i += stride) {
        int ci = i & 255;
        int o  = (i >> 8) & 511;
        int k  = i >> 17;
        float v = (o < 256) ? tw[(k * 256 + o) * 256 + ci]
                            : sw[(k * 256 + (o - 256)) * 256 + ci];
        Wts[i] = f2bf(v);
    }
    for (int i = idx; i < 256 * 256; i += stride) Wib[i] = f2bf(iw[i]);
    for (int i = idx; i < 256 * 256; i += stride) Wfb[i] = f2bf(fnw[i]);
}

// ---------------------------------------------------------------------------
__global__ void init_kernel(const float* __restrict__ x,
                            const float* __restrict__ init_w,
                            const float* __restrict__ init_b,
                            float* __restrict__ Hf,
                            unsigned short* __restrict__ Hb)
{
    const int j  = blockIdx.x;
    const int co = threadIdx.x;
    float acc = init_b[co];
    #pragma unroll
    for (int t = 0; t < 3; ++t) {
        int i = j + 2 * t - 2;
        if (i >= 0 && i < TS)
            acc += init_w[co * 3 + t] * x[(i & 1) * 4096 + (i >> 1)];
    }
    Hf[(j << 8) + co] = acc;
    Hb[(j << 8) + co] = f2bf(acc);
}

// ---------------------------------------------------------------------------
__global__ __launch_bounds__(512)
void iskip_kernel(const unsigned short* __restrict__ Hb,
                  const unsigned short* __restrict__ Wib,
                  const float* __restrict__ ib,
                  float* __restrict__ S)
{
    const int tid  = threadIdx.x;
    const int lane = tid & 63;
    const int w    = tid >> 6;
    const int j0   = blockIdx.x * 32;
    const int arow = lane & 15;
    const int krow = lane >> 4;
    const int c0   = w * 32;

    f32x4 acc[2][2];
    #pragma unroll
    for (int rt = 0; rt < 2; ++rt)
        #pragma unroll
        for (int fc = 0; fc < 2; ++fc) {
            const float b = ib[c0 + fc * 16 + arow];
            acc[rt][fc] = (f32x4){b, b, b, b};
        }

    #pragma unroll
    for (int kc = 0; kc < 8; ++kc) {
        const int koff = kc * 32 + krow * 8;
        const bf16x8 a0 = *(const bf16x8*)(Hb + ((j0 + arow) << 8) + koff);
        const bf16x8 a1 = *(const bf16x8*)(Hb + ((j0 + 16 + arow) << 8) + koff);
        const bf16x8 b0 = *(const bf16x8*)(Wib + ((c0 + arow) << 8) + koff);
        const bf16x8 b1 = *(const bf16x8*)(Wib + ((c0 + 16 + arow) << 8) + koff);
        acc[0][0] = __builtin_amdgcn_mfma_f32_16x16x32_bf16(a0, b0, acc[0][0], 0, 0, 0);
        acc[1][0] = __builtin_amdgcn_mfma_f32_16x16x32_bf16(a1, b0, acc[1][0], 0, 0, 0);
        acc[0][1] = __builtin_amdgcn_mfma_f32_16x16x32_bf16(a0, b1, acc[0][1], 0, 0, 0);
        acc[1][1] = __builtin_amdgcn_mfma_f32_16x16x32_bf16(a1, b1, acc[1][1], 0, 0, 0);
    }

    #pragma unroll
    for (int rt = 0; rt < 2; ++rt)
        #pragma unroll
        for (int fc = 0; fc < 2; ++fc)
            #pragma unroll
            for (int i = 0; i < 4; ++i) {
                const int row = rt * 16 + krow * 4 + i;
                S[((j0 + row) << 8) + c0 + fc * 16 + arow] = acc[rt][fc][i];
            }
}

// ---------------------------------------------------------------------------
// B-chunk staging: chunk c (0..23 = Wgf tap t=c>>3, kc=c&7; 24..31 = Wts kc).
// Wave w stages ONLY its own 64 rows (gate 32w.. + feat 256+32w.., or thru/skip
// 64w..) into its private LDS slice: [wave][buf][64 rows][32 K] bf16 = 4 KB.
// Linear LDS dest (global_load_lds requirement); 16B-slot XOR pre-swizzle on
// the SOURCE address, undone at read time (rule: both-sides-or-neither).
// ---------------------------------------------------------------------------
__device__ __forceinline__ void stage_chunk(
    const unsigned short* __restrict__ Wgf_k,
    const unsigned short* __restrict__ Wts_k,
    unsigned short* B_lds, int c, int w, int lane)
{
    const int buf  = c & 1;
    const int rsub = lane >> 2;                       // 0..15
    const int slot = (lane & 3) ^ ((lane >> 3) & 3);  // pre-swizzled src slot
    unsigned short* dst = B_lds + w * 4096 + buf * 2048;
    if (c < 24) {
        const int t = c >> 3, kc = c & 7;
        const int colbase = kc * 32 + slot * 8;
        const unsigned short* Wb = Wgf_k + (t * 512 + 32 * w) * 256 + colbase;
        #pragma unroll
        for (int q = 0; q < 4; ++q) {
            const int r_loc = q * 16 + rsub;                   // 0..63
            const int grow  = (q < 2) ? r_loc : (224 + r_loc); // feat at +256
            gload_lds16(Wb + grow * 256, dst + q * 512);
        }
    } else {
        const int kc = c - 24;
        const int colbase = kc * 32 + slot * 8;
        const unsigned short* Wb = Wts_k + (64 * w) * 256 + colbase;
        #pragma unroll
        for (int q = 0; q < 4; ++q) {
            const int r_loc = q * 16 + rsub;
            gload_lds16(Wb + r_loc * 256, dst + q * 512);
        }
    }
}

// read B fragment: local row r (0..63), k-quarter krow (0..3)
__device__ __forceinline__ bf16x8 bread(const unsigned short* Bw, int r, int krow)
{
    const int slot = krow ^ ((r >> 1) & 3);
    return *(const bf16x8*)(Bw + r * 32 + slot * 8);
}

// ---------------------------------------------------------------------------
// Fused layer kernel, pipelined. Block = 32 samples, 512 threads (8 waves).
// ---------------------------------------------------------------------------
__global__ __launch_bounds__(512)
void layer_kernel(const unsigned short* __restrict__ Hb_in,
                  const float* __restrict__ Hf_in,
                  float* __restrict__ Hf_out,
                  unsigned short* __restrict__ Hb_out,
                  const unsigned short* __restrict__ Wgf_k,  // [3][512][256]
                  const unsigned short* __restrict__ Wts_k,  // [512][256]
                  const float* __restrict__ gb,
                  const float* __restrict__ fb,
                  float* __restrict__ S,
                  unsigned short* __restrict__ Sb,
                  const int d, const int write_sb)
{
    __shared__ __align__(16) unsigned short A_lds[3 * 32 * 256];   // 48 KB
    __shared__ __align__(16) unsigned short res_lds[32 * 256];     // 16 KB
    __shared__ __align__(16) unsigned short B_lds[8 * 2 * 2048];   // 64 KB

    const int tid  = threadIdx.x;
    const int lane = tid & 63;
    const int w    = tid >> 6;
    const int j0   = blockIdx.x * 32;
    const int arow = lane & 15;
    const int krow = lane >> 4;

    // kick off chunk 0 before anything else (lands under A staging latency)
    stage_chunk(Wgf_k, Wts_k, B_lds, 0, w, lane);

    // ---- stage A: 3 taps x 32 rows x 256 ch, row-XOR swizzle (G4/T2) ----
    for (int cc = tid; cc < 3 * 32 * 32; cc += 512) {
        const int c16 = cc & 31;
        const int m   = (cc >> 5) & 31;
        const int t   = cc >> 10;
        const int r   = j0 + m + (t - 1) * d;
        uint4 v = make_uint4(0u, 0u, 0u, 0u);
        if (r >= 0 && r < TS)
            v = *(const uint4*)(Hb_in + (r << 8) + (c16 << 3));
        const int sb = (c16 << 4) ^ ((m & 7) << 4);
        *(uint4*)(A_lds + ((t * 32 + m) << 8) + (sb >> 1)) = v;
    }

    // biases / accumulator init
    const int cg0 = w * 32;
    f32x4 accG[2][2], accF[2][2];
    #pragma unroll
    for (int rt = 0; rt < 2; ++rt)
        #pragma unroll
        for (int fc = 0; fc < 2; ++fc) {
            const float g = gb[cg0 + fc * 16 + arow];
            const float f = fb[cg0 + fc * 16 + arow];
            accG[rt][fc] = (f32x4){g, g, g, g};
            accF[rt][fc] = (f32x4){f, f, f, f};
        }

    __syncthreads();   // A visible (also drains chunk-0 DMA)

    const int aswz = (arow & 7) << 4;

    // ---- phase 1: 24 chunks, barrier-free per-wave pipeline ----
    for (int c = 0; c < 24; ++c) {
        stage_chunk(Wgf_k, Wts_k, B_lds, c + 1, w, lane);
        WAITCNT_VM4();                       // chunk c landed (ours)
        const int t = c >> 3, kc = c & 7;
        const unsigned short* At = A_lds + ((t * 32 + arow) << 8);
        const int aoff = ((kc * 64 + krow * 16) ^ aswz) >> 1;
        const bf16x8 a0 = *(const bf16x8*)(At + aoff);
        const bf16x8 a1 = *(const bf16x8*)(At + (16 << 8) + aoff);
        const unsigned short* Bw = B_lds + w * 4096 + (c & 1) * 2048;
        const bf16x8 bg0 = bread(Bw, arow, krow);
        const bf16x8 bg1 = bread(Bw, 16 + arow, krow);
        const bf16x8 bf0 = bread(Bw, 32 + arow, krow);
        const bf16x8 bf1 = bread(Bw, 48 + arow, krow);
        accG[0][0] = __builtin_amdgcn_mfma_f32_16x16x32_bf16(a0, bg0, accG[0][0], 0, 0, 0);
        accG[1][0] = __builtin_amdgcn_mfma_f32_16x16x32_bf16(a1, bg0, accG[1][0], 0, 0, 0);
        accG[0][1] = __builtin_amdgcn_mfma_f32_16x16x32_bf16(a0, bg1, accG[0][1], 0, 0, 0);
        accG[1][1] = __builtin_amdgcn_mfma_f32_16x16x32_bf16(a1, bg1, accG[1][1], 0, 0, 0);
        accF[0][0] = __builtin_amdgcn_mfma_f32_16x16x32_bf16(a0, bf0, accF[0][0], 0, 0, 0);
        accF[1][0] = __builtin_amdgcn_mfma_f32_16x16x32_bf16(a1, bf0, accF[1][0], 0, 0, 0);
        accF[0][1] = __builtin_amdgcn_mfma_f32_16x16x32_bf16(a0, bf1, accF[0][1], 0, 0, 0);
        accF[1][1] = __builtin_amdgcn_mfma_f32_16x16x32_bf16(a1, bf1, accF[1][1], 0, 0, 0);
    }

    // stage chunk 25 so it flies during res computation (24 staged at c=23)
    stage_chunk(Wgf_k, Wts_k, B_lds, 25, w, lane);

    // ---- res = sigmoid(G)*tanh(F) -> swizzled LDS ----
    #pragma unroll
    for (int rt = 0; rt < 2; ++rt)
        #pragma unroll
        for (int fc = 0; fc < 2; ++fc)
            #pragma unroll
            for (int i = 0; i < 4; ++i) {
                const float g = accG[rt][fc][i];
                const float f = accF[rt][fc][i];
                const float sg = 1.0f / (1.0f + __expf(-g));
                const float e2 = __expf(2.0f * f);
                const float th = 1.0f - 2.0f / (e2 + 1.0f);
                const float rr = sg * th;
                const int row = rt * 16 + krow * 4 + i;
                const int col = cg0 + fc * 16 + arow;
                res_lds[(row << 8) + (((col << 1) ^ ((row & 7) << 4)) >> 1)] = f2bf(rr);
            }
    __syncthreads();   // res visible to all waves (drains chunks 24,25)

    // ---- phase 2: 8 chunks (out cols [64w, 64w+64)) ----
    f32x4 acc2[2][4];
    #pragma unroll
    for (int rt = 0; rt < 2; ++rt)
        #pragma unroll
        for (int fc = 0; fc < 4; ++fc)
            acc2[rt][fc] = (f32x4){0.f, 0.f, 0.f, 0.f};

    const int c0 = w * 64;
    for (int c2 = 0; c2 < 8; ++c2) {
        if (c2 >= 1 && c2 <= 6) {
            stage_chunk(Wgf_k, Wts_k, B_lds, 25 + c2, w, lane);
            WAITCNT_VM4();
        } else {
            WAITCNT_VM0();
        }
        const int kc2 = c2;
        const int aoff = ((kc2 * 64 + krow * 16) ^ aswz) >> 1;
        const bf16x8 a0 = *(const bf16x8*)(res_lds + (arow << 8) + aoff);
        const bf16x8 a1 = *(const bf16x8*)(res_lds + ((16 + arow) << 8) + aoff);
        const unsigned short* Bw = B_lds + w * 4096 + (c2 & 1) * 2048;
        #pragma unroll
        for (int fc = 0; fc < 4; ++fc) {
            const bf16x8 b = bread(Bw, fc * 16 + arow, krow);
            acc2[0][fc] = __builtin_amdgcn_mfma_f32_16x16x32_bf16(a0, b, acc2[0][fc], 0, 0, 0);
            acc2[1][fc] = __builtin_amdgcn_mfma_f32_16x16x32_bf16(a1, b, acc2[1][fc], 0, 0, 0);
        }
    }

    // ---- epilogue: waves 0..3 -> H residual update; waves 4..7 -> S RMW ----
    if (w < 4) {
        #pragma unroll
        for (int rt = 0; rt < 2; ++rt)
            #pragma unroll
            for (int fc = 0; fc < 4; ++fc)
                #pragma unroll
                for (int i = 0; i < 4; ++i) {
                    const int row = rt * 16 + krow * 4 + i;
                    const int cc  = c0 + fc * 16 + arow;
                    const int g   = ((j0 + row) << 8) + cc;
                    const float v = Hf_in[g] + acc2[rt][fc][i];
                    Hf_out[g] = v;
                    Hb_out[g] = f2bf(v);
                }
    } else {
        const int cs0 = c0 - 256;
        #pragma unroll
        for (int rt = 0; rt < 2; ++rt)
            #pragma unroll
            for (int fc = 0; fc < 4; ++fc)
                #pragma unroll
                for (int i = 0; i < 4; ++i) {
                    const int row = rt * 16 + krow * 4 + i;
                    const int so  = cs0 + fc * 16 + arow;
                    const int g   = ((j0 + row) << 8) + so;
                    const float v = S[g] + acc2[rt][fc][i];
                    S[g] = v;
                    if (write_sb) Sb[g] = f2bf(v);
                }
    }
}

// ---------------------------------------------------------------------------
__global__ __launch_bounds__(512)
void final_kernel(const unsigned short* __restrict__ Sb,
                  const unsigned short* __restrict__ Wfb,
                  const float* __restrict__ fbias,
                  float* __restrict__ out)
{
    const int tid  = threadIdx.x;
    const int lane = tid & 63;
    const int w    = tid >> 6;
    const int j0   = blockIdx.x * 32;
    const int arow = lane & 15;
    const int krow = lane >> 4;
    const int m0   = w * 32;

    f32x4 acc[2][2];
    #pragma unroll
    for (int rt = 0; rt < 2; ++rt)
        #pragma unroll
        for (int fc = 0; fc < 2; ++fc)
            acc[rt][fc] = (f32x4){0.f, 0.f, 0.f, 0.f};

    #pragma unroll
    for (int kc = 0; kc < 8; ++kc) {
        const int koff = kc * 32 + krow * 8;
        const bf16x8 a0 = *(const bf16x8*)(Wfb + ((m0 + arow) << 8) + koff);
        const bf16x8 a1 = *(const bf16x8*)(Wfb + ((m0 + 16 + arow) << 8) + koff);
        const bf16x8 b0 = *(const bf16x8*)(Sb + ((j0 + arow) << 8) + koff);
        const bf16x8 b1 = *(const bf16x8*)(Sb + ((j0 + 16 + arow) << 8) + koff);
        acc[0][0] = __builtin_amdgcn_mfma_f32_16x16x32_bf16(a0, b0, acc[0][0], 0, 0, 0);
        acc[1][0] = __builtin_amdgcn_mfma_f32_16x16x32_bf16(a1, b0, acc[1][0], 0, 0, 0);
        acc[0][1] = __builtin_amdgcn_mfma_f32_16x16x32_bf16(a0, b1, acc[0][1], 0, 0, 0);
        acc[1][1] = __builtin_amdgcn_mfma_f32_16x16x32_bf16(a1, b1, acc[1][1], 0, 0, 0);
    }

    #pragma unroll
    for (int rt = 0; rt < 2; ++rt)
        #pragma unroll
        for (int fc = 0; fc < 2; ++fc)
            #pragma unroll
            for (int i = 0; i < 4; ++i) {
                const int co = m0 + rt * 16 + krow * 4 + i;
                const int jj = j0 + fc * 16 + arow;
                out[((jj & 1) << 20) + (co << 12) + (jj >> 1)] = acc[rt][fc][i] + fbias[co];
            }
}

// ---------------------------------------------------------------------------
extern "C" void kernel_launch(void* const* d_in, const int* in_sizes, int n_in,
                              void* d_out, int out_size, void* d_ws, size_t ws_size,
                              hipStream_t stream)
{
    const float* x       = (const float*)d_in[0];
    const float* init_w  = (const float*)d_in[1];
    const float* init_b  = (const float*)d_in[2];
    const float* iskip_w = (const float*)d_in[3];
    const float* iskip_b = (const float*)d_in[4];
    const float* gate_w  = (const float*)d_in[5];
    const float* gate_b  = (const float*)d_in[6];
    const float* feat_w  = (const float*)d_in[7];
    const float* feat_b  = (const float*)d_in[8];
    const float* skip_w  = (const float*)d_in[9];
    const float* thru_w  = (const float*)d_in[10];
    const float* final_w = (const float*)d_in[11];
    const float* final_b = (const float*)d_in[12];

    char* ws = (char*)d_ws;
    size_t off = 0;
    auto alloc = [&](size_t bytes) {
        void* p = ws + off;
        off += (bytes + 255) & ~(size_t)255;
        return p;
    };
    unsigned short* Wgf = (unsigned short*)alloc((size_t)NL * 3 * 512 * 256 * 2);
    unsigned short* Wts = (unsigned short*)alloc((size_t)NL * 512 * 256 * 2);
    unsigned short* Wib = (unsigned short*)alloc(256 * 256 * 2);
    unsigned short* Wfb = (unsigned short*)alloc(256 * 256 * 2);
    float*          Hf0 = (float*)alloc((size_t)TS * 256 * 4);
    float*          Hf1 = (float*)alloc((size_t)TS * 256 * 4);
    unsigned short* Hb0 = (unsigned short*)alloc((size_t)TS * 256 * 2);
    unsigned short* Hb1 = (unsigned short*)alloc((size_t)TS * 256 * 2);
    float*          Sf  = (float*)alloc((size_t)TS * 256 * 4);
    unsigned short* Sbb = (unsigned short*)alloc((size_t)TS * 256 * 2);

    prep_weights_kernel<<<2048, 256, 0, stream>>>(gate_w, feat_w, thru_w, skip_w,
                                                  iskip_w, final_w, Wgf, Wts, Wib, Wfb);
    init_kernel<<<TS, 256, 0, stream>>>(x, init_w, init_b, Hf0, Hb0);
    iskip_kernel<<<256, 512, 0, stream>>>(Hb0, Wib, iskip_b, Sf);

    float* hfi = Hf0;          float* hfo = Hf1;
    unsigned short* hbi = Hb0; unsigned short* hbo = Hb1;
    for (int k = 0; k < NL; ++k) {
        const int d = 2 << (k % 10);   // stream dilation = 2 * 2^(k%10)
        layer_kernel<<<256, 512, 0, stream>>>(
            hbi, hfi, hfo, hbo,
            Wgf + (size_t)k * 3 * 512 * 256,
            Wts + (size_t)k * 512 * 256,
            gate_b + k * 256, feat_b + k * 256,
            Sf, Sbb, d, (k == NL - 1) ? 1 : 0);
        float* tf = hfi; hfi = hfo; hfo = tf;
        unsigned short* tb = hbi; hbi = hbo; hbo = tb;
    }

    final_kernel<<<256, 512, 0, stream>>>(Sbb, Wfb, final_b, (float*)d_out);
}